// Round 1
// 872.139 us; speedup vs baseline: 1.0501x; 1.0501x over previous
//
#include <hip/hip_runtime.h>

// ---------- types / helpers ----------
typedef __bf16 bf16x8 __attribute__((ext_vector_type(8)));
typedef float  f32x4  __attribute__((ext_vector_type(4)));

#define EPSC 1e-6f

__device__ __forceinline__ unsigned short f2bf(float f) {
  union { float f; unsigned int u; } c; c.f = f;
  unsigned int u = c.u;
  u = u + 0x7FFFu + ((u >> 16) & 1u);   // RNE
  return (unsigned short)(u >> 16);
}
__device__ __forceinline__ float bf2f(unsigned short h) {
  union { unsigned int u; float f; } c; c.u = ((unsigned int)h) << 16;
  return c.f;
}
__device__ __forceinline__ void gl_lds16(const unsigned short* g, unsigned short* l) {
  __builtin_amdgcn_global_load_lds((const __attribute__((address_space(1))) void*)g,
                                   (__attribute__((address_space(3))) void*)l, 16, 0, 0);
}

template<int N> __device__ __forceinline__ void waitvm() {
  if constexpr (N == 8)      asm volatile("s_waitcnt vmcnt(8)" ::: "memory");
  else if constexpr (N == 4) asm volatile("s_waitcnt vmcnt(4)" ::: "memory");
  else                       asm volatile("s_waitcnt vmcnt(0)" ::: "memory");
}

// ---------- K1: fused Cayley (blocks 0..23) + x fp32->bf16 convert (blocks 24+) ----------
// (unchanged from previous round)
__global__ void __launch_bounds__(512) cayley_cvt_k(const float* __restrict__ qR,
                                                    const float* __restrict__ kR,
                                                    const float* __restrict__ vR,
                                                    float* __restrict__ wsL,
                                                    float* __restrict__ wsQt,
                                                    const float4* __restrict__ xin,
                                                    ushort4* __restrict__ xbf,
                                                    int n4) {
  extern __shared__ float A_s[];      // [128][128]
  const int tid = threadIdx.x;

  if (blockIdx.x >= 24) {
    int i = (blockIdx.x - 24) * 512 + tid;
    int stride = (gridDim.x - 24) * 512;
    for (; i < n4; i += stride) {
      float4 v = xin[i];
      ushort4 o;
      o.x = f2bf(v.x); o.y = f2bf(v.y); o.z = f2bf(v.z); o.w = f2bf(v.w);
      xbf[i] = o;
    }
    return;
  }

  float4* A4 = (float4*)A_s;          // [128][32]
  const int m = blockIdx.x;           // 0..23
  const float* R = (m < 8 ? qR : (m < 16 ? kR : vR)) + (size_t)(m & 7) * 16384;
  float* Lg = wsL  + (size_t)m * 16384;
  float* Qt = wsQt + (size_t)m * 16384;

  for (int idx = tid; idx < 16384; idx += 512) {
    int i = idx >> 7, j = idx & 127;
    float s = 0.5f * (R[idx] - R[j * 128 + i]);
    float v = ((i == j) ? (1.0f + EPSC) : 0.0f) - s;
    A_s[idx] = v;
    Lg[idx] = v;
  }

  const int c = tid & 31;
  const int rg = tid >> 5;
  for (int k = 0; k < 128; ++k) {
    __syncthreads();
    if (tid < 32) {
      float ip = 1.0f / A_s[k * 128 + k];
      float4 v = A4[k * 32 + tid];
      v.x *= ip; v.y *= ip; v.z *= ip; v.w *= ip;
      if (tid == (k >> 2)) {
        int k3 = k & 3;
        if (k3 == 0) v.x = ip; else if (k3 == 1) v.y = ip;
        else if (k3 == 2) v.z = ip; else v.w = ip;
      }
      A4[k * 32 + tid] = v;
    }
    __syncthreads();

    float4 rk = A4[k * 32 + c];
    const int kc = k >> 2, k3 = k & 3;
    const float ipv = (k3 == 0) ? rk.x : (k3 == 1) ? rk.y : (k3 == 2) ? rk.z : rk.w;

    float mi[8];
    float4 v[8];
#pragma unroll
    for (int p = 0; p < 8; ++p) mi[p] = A_s[(p * 16 + rg) * 128 + k];
#pragma unroll
    for (int p = 0; p < 8; ++p) v[p] = A4[(p * 16 + rg) * 32 + c];
#pragma unroll
    for (int p = 0; p < 8; ++p) {
      const int i = p * 16 + rg;
      const bool isk = (i == k);
      const float mm = isk ? 0.0f : mi[p];
      float4 w = v[p];
      w.x -= mm * rk.x; w.y -= mm * rk.y; w.z -= mm * rk.z; w.w -= mm * rk.w;
      if (c == kc && !isk) {
        const float fx = -mm * ipv;
        if (k3 == 0) w.x = fx; else if (k3 == 1) w.y = fx;
        else if (k3 == 2) w.z = fx; else w.w = fx;
      }
      A4[i * 32 + c] = w;
    }
  }
  __syncthreads();

  const int ti = tid >> 4, tj = tid & 15;
  const int i0 = ti * 4, j0 = tj * 8;
  float acc[4][8];
#pragma unroll
  for (int r = 0; r < 4; ++r)
#pragma unroll
    for (int s = 0; s < 8; ++s) acc[r][s] = 0.f;

  for (int tc = 0; tc < 32; ++tc) {
    float4 b4[8];
#pragma unroll
    for (int s = 0; s < 8; ++s)
      b4[s] = *(const float4*)&Lg[(size_t)(j0 + s) * 128 + tc * 4];
#pragma unroll
    for (int r = 0; r < 4; ++r) {
      float4 a4 = A4[(i0 + r) * 32 + tc];
#pragma unroll
      for (int s = 0; s < 8; ++s)
        acc[r][s] += a4.x * b4[s].x + a4.y * b4[s].y + a4.z * b4[s].z + a4.w * b4[s].w;
    }
  }
#pragma unroll
  for (int r = 0; r < 4; ++r)
#pragma unroll
    for (int s = 0; s < 8; ++s) {
      float v = acc[r][s] - EPSC * A_s[(i0 + r) * 128 + j0 + s];
      Qt[(size_t)(i0 + r) * 128 + j0 + s] = v;
    }
}

// ---------- K2: filt[o][n*128+c] = sum_b W[o][n*128+b] * Qt_m[c][b]  (bf16 out) ----------
// (unchanged from previous round)
__global__ void __launch_bounds__(256) filt_k(const float* __restrict__ W,
                                              const float* __restrict__ wsQt,
                                              unsigned short* __restrict__ filt) {
  __shared__ unsigned short Qs[128 * 136];
  const int m = blockIdx.x;
  const int ot = blockIdx.y;
  const int mset = m >> 3, n = m & 7;
  const float* Qt = wsQt + (size_t)m * 16384;
  const int tid = threadIdx.x;

  for (int idx = tid; idx < 16384; idx += 256) {
    int i = idx >> 7, j = idx & 127;
    Qs[i * 136 + j] = f2bf(Qt[idx]);
  }
  __syncthreads();

  const int ol = tid & 63, cg = tid >> 6;
  const int go = mset * 1024 + ot * 64 + ol;
  const float* Wrow = W + (size_t)go * 1024 + n * 128;

  float acc[32];
#pragma unroll
  for (int i = 0; i < 32; ++i) acc[i] = 0.f;

  for (int b4 = 0; b4 < 32; ++b4) {
    float4 w4 = *(const float4*)(Wrow + b4 * 4);
#pragma unroll
    for (int cc = 0; cc < 32; ++cc) {
      int cidx = cg * 32 + cc;
      ushort4 q4 = *(const ushort4*)&Qs[cidx * 136 + b4 * 4];
      acc[cc] += w4.x * bf2f(q4.x) + w4.y * bf2f(q4.y)
               + w4.z * bf2f(q4.z) + w4.w * bf2f(q4.w);
    }
  }
  unsigned short* dst = filt + (size_t)go * 1024 + n * 128 + cg * 32;
#pragma unroll
  for (int g2 = 0; g2 < 8; ++g2) {
    ushort4 o;
    o.x = f2bf(acc[g2 * 4 + 0]); o.y = f2bf(acc[g2 * 4 + 1]);
    o.z = f2bf(acc[g2 * 4 + 2]); o.w = f2bf(acc[g2 * 4 + 3]);
    *(ushort4*)(dst + g2 * 4) = o;
  }
}

// ---------- K3: C[M,N] = A[M,K] @ B[N,K]^T + bias, bf16 MFMA ----------
// NEW: 256x256 tile, BK=32, 4-deep LDS ring (4 x 32KB = 128KB dynamic LDS),
// one raw s_barrier per K-step, counted vmcnt(8) (loads for tiles t+1,t+2 stay
// in flight across barriers -- never drained to 0 in the main loop), XOR
// bank-swizzle (involution P = L ^ (((L>>7)&3)<<4), applied to BOTH the
// global-load source address and the ds_read offsets; LDS dest stays linear
// as global_load_lds requires), setprio(1) around the MFMA cluster.
// Ring safety is structural: stage(t+2) targets buf[(t+2)&3], whose last
// ds_read completed before the barrier of step t-1, which every wave has
// passed before any wave issues stage(t+2).
// grid (12, 128) x 512 threads (8 waves: 2 M x 4 N), per-wave C = 128x64.
__global__ void __launch_bounds__(512, 2) gemm_k(const unsigned short* __restrict__ Ax,
                                                 const unsigned short* __restrict__ Bf,
                                                 const float* __restrict__ bias,
                                                 float* __restrict__ C) {
  extern __shared__ char smem_g[];          // 4 x (A 16KB + B 16KB)
  const int tid = threadIdx.x;
  const int lane = tid & 63, wave = tid >> 6;
  const int wm = wave & 1, wn = wave >> 1;   // 2 x 4 wave grid
  const int quad = lane >> 4, l16 = lane & 15;
  const long mbase = (long)blockIdx.y * 256;
  const long nbase = (long)blockIdx.x * 256;

  // ---- staging setup: thread covers 2 x 16B chunks of A-tile and of B-tile.
  // Linear LDS dest D (= wave-uniform base + lane*16, required by
  // global_load_lds); the global SOURCE is pre-swizzled: element at logical
  // tile offset L = D ^ f(D) lands at physical D, so reads use P = L ^ f(L).
  const unsigned short* gA0; const unsigned short* gA1;
  const unsigned short* gB0; const unsigned short* gB1;
  int dof0, dof1;
  {
    int D0 = 0 * 8192 + tid * 16;
    int D1 = 1 * 8192 + tid * 16;
    int L0 = D0 ^ (((D0 >> 7) & 3) << 4);
    int L1 = D1 ^ (((D1 >> 7) & 3) << 4);
    int r0 = L0 >> 6, c0 = (L0 & 63) >> 1;   // tile row (0..255), k element (0..31)
    int r1 = L1 >> 6, c1 = (L1 & 63) >> 1;
    gA0 = Ax + (size_t)(mbase + r0) * 1024 + c0;
    gA1 = Ax + (size_t)(mbase + r1) * 1024 + c1;
    gB0 = Bf + (size_t)(nbase + r0) * 1024 + c0;
    gB1 = Bf + (size_t)(nbase + r1) * 1024 + c1;
    dof0 = D0; dof1 = D1;
  }

  // ---- fragment ds_read byte offsets (swizzled), fixed for the whole K loop
  int aoff[8], boff[4];
#pragma unroll
  for (int mi = 0; mi < 8; ++mi) {
    int row = wm * 128 + mi * 16 + l16;
    int L = row * 64 + quad * 16;
    aoff[mi] = L ^ (((L >> 7) & 3) << 4);
  }
#pragma unroll
  for (int ni = 0; ni < 4; ++ni) {
    int row = wn * 64 + ni * 16 + l16;
    int L = row * 64 + quad * 16;
    boff[ni] = 16384 + (L ^ (((L >> 7) & 3) << 4));
  }

  f32x4 acc[8][4];
#pragma unroll
  for (int mi = 0; mi < 8; ++mi)
#pragma unroll
    for (int ni = 0; ni < 4; ++ni) {
      acc[mi][ni][0] = 0.f; acc[mi][ni][1] = 0.f;
      acc[mi][ni][2] = 0.f; acc[mi][ni][3] = 0.f;
    }

#define GSTAGE(T)                                                              \
  {                                                                            \
    char* sb = smem_g + ((T) & 3) * 32768;                                     \
    gl_lds16(gA0 + (T) * 32, (unsigned short*)(sb + dof0));                    \
    gl_lds16(gA1 + (T) * 32, (unsigned short*)(sb + dof1));                    \
    gl_lds16(gB0 + (T) * 32, (unsigned short*)(sb + 16384 + dof0));            \
    gl_lds16(gB1 + (T) * 32, (unsigned short*)(sb + 16384 + dof1));            \
  }

#define GSTEP(T, VM)                                                           \
  {                                                                            \
    waitvm<VM>();                                                              \
    __builtin_amdgcn_s_barrier();                                              \
    asm volatile("" ::: "memory");                                             \
    const char* bb = smem_g + ((T) & 3) * 32768;                               \
    bf16x8 bfr[4], afr[8];                                                     \
    _Pragma("unroll")                                                          \
    for (int ni = 0; ni < 4; ++ni) bfr[ni] = *(const bf16x8*)(bb + boff[ni]);  \
    _Pragma("unroll")                                                          \
    for (int mi = 0; mi < 8; ++mi) afr[mi] = *(const bf16x8*)(bb + aoff[mi]);  \
    __builtin_amdgcn_s_setprio(1);                                             \
    _Pragma("unroll")                                                          \
    for (int mi = 0; mi < 8; ++mi)                                             \
      _Pragma("unroll")                                                        \
      for (int ni = 0; ni < 4; ++ni)                                           \
        acc[mi][ni] = __builtin_amdgcn_mfma_f32_16x16x32_bf16(                 \
            afr[mi], bfr[ni], acc[mi][ni], 0, 0, 0);                           \
    __builtin_amdgcn_s_setprio(0);                                             \
  }

  // prologue: tiles 0 and 1 in flight
  GSTAGE(0);
  GSTAGE(1);

  // main loop: 32 K-steps of 32. Steady state keeps 8 loads (2 tiles) in
  // flight; vmcnt(8) guarantees tile T's 4 loads have landed, the barrier
  // makes that true for all waves' loads.
  for (int t = 0; t < 30; ++t) {
    GSTAGE(t + 2);
    GSTEP(t, 8);
  }
  GSTEP(30, 4);
  GSTEP(31, 0);

#undef GSTAGE
#undef GSTEP

  // epilogue: D row = quad*4 + r (M dim), col = l16 (N dim)
#pragma unroll
  for (int ni = 0; ni < 4; ++ni) {
    long gcol = nbase + wn * 64 + ni * 16 + l16;
    float bv = bias[gcol];
#pragma unroll
    for (int mi = 0; mi < 8; ++mi) {
      long grow = mbase + wm * 128 + mi * 16 + quad * 4;
#pragma unroll
      for (int r = 0; r < 4; ++r)
        C[(grow + r) * 3072 + gcol] = acc[mi][ni][r] + bv;
    }
  }
}

// ---------- launcher ----------
extern "C" void kernel_launch(void* const* d_in, const int* in_sizes, int n_in,
                              void* d_out, int out_size, void* d_ws, size_t ws_size,
                              hipStream_t stream) {
  const float* W    = (const float*)d_in[0];  // [3072,1024]
  const float* bias = (const float*)d_in[1];  // [3072]
  const float* x    = (const float*)d_in[2];  // [8,4096,1024]
  const float* qR   = (const float*)d_in[3];  // [8,128,128]
  const float* kR   = (const float*)d_in[4];
  const float* vR   = (const float*)d_in[5];
  float* out = (float*)d_out;                 // [8,4096,3072]

  char* ws = (char*)d_ws;
  float* wsL           = (float*)(ws);                       // 1.5 MB
  float* wsQt          = (float*)(ws + 1572864);             // 1.5 MB
  unsigned short* wsF  = (unsigned short*)(ws + 3145728);    // 6 MB  (filt bf16)
  unsigned short* wsX  = (unsigned short*)(ws + 9437184);    // 64 MB (x bf16)

  static bool attr_done = false;
  if (!attr_done) {
    (void)hipFuncSetAttribute(reinterpret_cast<const void*>(gemm_k),
                              hipFuncAttributeMaxDynamicSharedMemorySize, 131072);
    attr_done = true;
  }

  cayley_cvt_k<<<24 + 2048, 512, 65536, stream>>>(qR, kR, vR, wsL, wsQt,
                                                  (const float4*)x, (ushort4*)wsX,
                                                  33554432 / 4);
  filt_k<<<dim3(24, 16), 256, 0, stream>>>(W, wsQt, wsF);
  gemm_k<<<dim3(12, 128), 512, 131072, stream>>>(wsX, wsF, bias, out);
}

// Round 2
// 858.430 us; speedup vs baseline: 1.0669x; 1.0160x over previous
//
#include <hip/hip_runtime.h>

// ---------- types / helpers ----------
typedef __bf16 bf16x8 __attribute__((ext_vector_type(8)));
typedef float  f32x4  __attribute__((ext_vector_type(4)));

#define EPSC 1e-6f

__device__ __forceinline__ unsigned short f2bf(float f) {
  union { float f; unsigned int u; } c; c.f = f;
  unsigned int u = c.u;
  u = u + 0x7FFFu + ((u >> 16) & 1u);   // RNE
  return (unsigned short)(u >> 16);
}
__device__ __forceinline__ float bf2f(unsigned short h) {
  union { unsigned int u; float f; } c; c.u = ((unsigned int)h) << 16;
  return c.f;
}
__device__ __forceinline__ void gl_lds16(const unsigned short* g, unsigned short* l) {
  __builtin_amdgcn_global_load_lds((const __attribute__((address_space(1))) void*)g,
                                   (__attribute__((address_space(3))) void*)l, 16, 0, 0);
}

// ---------- K1: fused Cayley (blocks 0..23) + x fp32->bf16 convert (blocks 24+) ----------
// (unchanged)
__global__ void __launch_bounds__(512) cayley_cvt_k(const float* __restrict__ qR,
                                                    const float* __restrict__ kR,
                                                    const float* __restrict__ vR,
                                                    float* __restrict__ wsL,
                                                    float* __restrict__ wsQt,
                                                    const float4* __restrict__ xin,
                                                    ushort4* __restrict__ xbf,
                                                    int n4) {
  extern __shared__ float A_s[];      // [128][128]
  const int tid = threadIdx.x;

  if (blockIdx.x >= 24) {
    int i = (blockIdx.x - 24) * 512 + tid;
    int stride = (gridDim.x - 24) * 512;
    for (; i < n4; i += stride) {
      float4 v = xin[i];
      ushort4 o;
      o.x = f2bf(v.x); o.y = f2bf(v.y); o.z = f2bf(v.z); o.w = f2bf(v.w);
      xbf[i] = o;
    }
    return;
  }

  float4* A4 = (float4*)A_s;          // [128][32]
  const int m = blockIdx.x;           // 0..23
  const float* R = (m < 8 ? qR : (m < 16 ? kR : vR)) + (size_t)(m & 7) * 16384;
  float* Lg = wsL  + (size_t)m * 16384;
  float* Qt = wsQt + (size_t)m * 16384;

  for (int idx = tid; idx < 16384; idx += 512) {
    int i = idx >> 7, j = idx & 127;
    float s = 0.5f * (R[idx] - R[j * 128 + i]);
    float v = ((i == j) ? (1.0f + EPSC) : 0.0f) - s;
    A_s[idx] = v;
    Lg[idx] = v;
  }

  const int c = tid & 31;
  const int rg = tid >> 5;
  for (int k = 0; k < 128; ++k) {
    __syncthreads();
    if (tid < 32) {
      float ip = 1.0f / A_s[k * 128 + k];
      float4 v = A4[k * 32 + tid];
      v.x *= ip; v.y *= ip; v.z *= ip; v.w *= ip;
      if (tid == (k >> 2)) {
        int k3 = k & 3;
        if (k3 == 0) v.x = ip; else if (k3 == 1) v.y = ip;
        else if (k3 == 2) v.z = ip; else v.w = ip;
      }
      A4[k * 32 + tid] = v;
    }
    __syncthreads();

    float4 rk = A4[k * 32 + c];
    const int kc = k >> 2, k3 = k & 3;
    const float ipv = (k3 == 0) ? rk.x : (k3 == 1) ? rk.y : (k3 == 2) ? rk.z : rk.w;

    float mi[8];
    float4 v[8];
#pragma unroll
    for (int p = 0; p < 8; ++p) mi[p] = A_s[(p * 16 + rg) * 128 + k];
#pragma unroll
    for (int p = 0; p < 8; ++p) v[p] = A4[(p * 16 + rg) * 32 + c];
#pragma unroll
    for (int p = 0; p < 8; ++p) {
      const int i = p * 16 + rg;
      const bool isk = (i == k);
      const float mm = isk ? 0.0f : mi[p];
      float4 w = v[p];
      w.x -= mm * rk.x; w.y -= mm * rk.y; w.z -= mm * rk.z; w.w -= mm * rk.w;
      if (c == kc && !isk) {
        const float fx = -mm * ipv;
        if (k3 == 0) w.x = fx; else if (k3 == 1) w.y = fx;
        else if (k3 == 2) w.z = fx; else w.w = fx;
      }
      A4[i * 32 + c] = w;
    }
  }
  __syncthreads();

  const int ti = tid >> 4, tj = tid & 15;
  const int i0 = ti * 4, j0 = tj * 8;
  float acc[4][8];
#pragma unroll
  for (int r = 0; r < 4; ++r)
#pragma unroll
    for (int s = 0; s < 8; ++s) acc[r][s] = 0.f;

  for (int tc = 0; tc < 32; ++tc) {
    float4 b4[8];
#pragma unroll
    for (int s = 0; s < 8; ++s)
      b4[s] = *(const float4*)&Lg[(size_t)(j0 + s) * 128 + tc * 4];
#pragma unroll
    for (int r = 0; r < 4; ++r) {
      float4 a4 = A4[(i0 + r) * 32 + tc];
#pragma unroll
      for (int s = 0; s < 8; ++s)
        acc[r][s] += a4.x * b4[s].x + a4.y * b4[s].y + a4.z * b4[s].z + a4.w * b4[s].w;
    }
  }
#pragma unroll
  for (int r = 0; r < 4; ++r)
#pragma unroll
    for (int s = 0; s < 8; ++s) {
      float v = acc[r][s] - EPSC * A_s[(i0 + r) * 128 + j0 + s];
      Qt[(size_t)(i0 + r) * 128 + j0 + s] = v;
    }
}

// ---------- K2: filt[o][n*128+c] = sum_b W[o][n*128+b] * Qt_m[c][b]  (bf16 out) ----------
// (unchanged)
__global__ void __launch_bounds__(256) filt_k(const float* __restrict__ W,
                                              const float* __restrict__ wsQt,
                                              unsigned short* __restrict__ filt) {
  __shared__ unsigned short Qs[128 * 136];
  const int m = blockIdx.x;
  const int ot = blockIdx.y;
  const int mset = m >> 3, n = m & 7;
  const float* Qt = wsQt + (size_t)m * 16384;
  const int tid = threadIdx.x;

  for (int idx = tid; idx < 16384; idx += 256) {
    int i = idx >> 7, j = idx & 127;
    Qs[i * 136 + j] = f2bf(Qt[idx]);
  }
  __syncthreads();

  const int ol = tid & 63, cg = tid >> 6;
  const int go = mset * 1024 + ot * 64 + ol;
  const float* Wrow = W + (size_t)go * 1024 + n * 128;

  float acc[32];
#pragma unroll
  for (int i = 0; i < 32; ++i) acc[i] = 0.f;

  for (int b4 = 0; b4 < 32; ++b4) {
    float4 w4 = *(const float4*)(Wrow + b4 * 4);
#pragma unroll
    for (int cc = 0; cc < 32; ++cc) {
      int cidx = cg * 32 + cc;
      ushort4 q4 = *(const ushort4*)&Qs[cidx * 136 + b4 * 4];
      acc[cc] += w4.x * bf2f(q4.x) + w4.y * bf2f(q4.y)
               + w4.z * bf2f(q4.z) + w4.w * bf2f(q4.w);
    }
  }
  unsigned short* dst = filt + (size_t)go * 1024 + n * 128 + cg * 32;
#pragma unroll
  for (int g2 = 0; g2 < 8; ++g2) {
    ushort4 o;
    o.x = f2bf(acc[g2 * 4 + 0]); o.y = f2bf(acc[g2 * 4 + 1]);
    o.z = f2bf(acc[g2 * 4 + 2]); o.w = f2bf(acc[g2 * 4 + 3]);
    *(ushort4*)(dst + g2 * 4) = o;
  }
}

// ---------- K3: C[M,N] = A[M,K] @ B[N,K]^T + bias, bf16 MFMA ----------
// Round-2: two fine phases per K-step (m201-style interleave) on the verified
// 4-deep ring. Per phase: {ds_read frag subset || stage half-tile} -> s_barrier
// -> lgkmcnt(0)+sched_barrier(0) -> setprio(1) -> 16 MFMA -> setprio(0) ->
// s_barrier. Prefetch 3 K-steps ahead; steady-state vmcnt(8) at phase B drains
// exactly tile t+1's 4 loads (issued 6 phases earlier). Swizzle unchanged
// (0 conflicts measured). grid (12, 128) x 512 threads (2M x 4N waves).
__global__ void __launch_bounds__(512, 2) gemm_k(const unsigned short* __restrict__ Ax,
                                                 const unsigned short* __restrict__ Bf,
                                                 const float* __restrict__ bias,
                                                 float* __restrict__ C) {
  extern __shared__ char smem_g[];          // 4 x (A 16KB + B 16KB)
  const int tid = threadIdx.x;
  const int lane = tid & 63, wave = tid >> 6;
  const int wm = wave & 1, wn = wave >> 1;   // 2 x 4 wave grid
  const int quad = lane >> 4, l16 = lane & 15;
  const long mbase = (long)blockIdx.y * 256;
  const long nbase = (long)blockIdx.x * 256;

  // staging: linear LDS dest D, pre-swizzled global source (involution
  // P = L ^ (((L>>7)&3)<<4), same as the zero-conflict round-1 layout)
  const unsigned short* gA0; const unsigned short* gA1;
  const unsigned short* gB0; const unsigned short* gB1;
  int dof0, dof1;
  {
    int D0 = 0 * 8192 + tid * 16;
    int D1 = 1 * 8192 + tid * 16;
    int L0 = D0 ^ (((D0 >> 7) & 3) << 4);
    int L1 = D1 ^ (((D1 >> 7) & 3) << 4);
    int r0 = L0 >> 6, c0 = (L0 & 63) >> 1;
    int r1 = L1 >> 6, c1 = (L1 & 63) >> 1;
    gA0 = Ax + (size_t)(mbase + r0) * 1024 + c0;
    gA1 = Ax + (size_t)(mbase + r1) * 1024 + c1;
    gB0 = Bf + (size_t)(nbase + r0) * 1024 + c0;
    gB1 = Bf + (size_t)(nbase + r1) * 1024 + c1;
    dof0 = D0; dof1 = D1;
  }

  // fragment ds_read byte offsets (swizzled), fixed for the whole K loop
  int aoff[8], boff[4];
#pragma unroll
  for (int mi = 0; mi < 8; ++mi) {
    int row = wm * 128 + mi * 16 + l16;
    int L = row * 64 + quad * 16;
    aoff[mi] = L ^ (((L >> 7) & 3) << 4);
  }
#pragma unroll
  for (int ni = 0; ni < 4; ++ni) {
    int row = wn * 64 + ni * 16 + l16;
    int L = row * 64 + quad * 16;
    boff[ni] = 16384 + (L ^ (((L >> 7) & 3) << 4));
  }

  f32x4 acc[8][4];
#pragma unroll
  for (int mi = 0; mi < 8; ++mi)
#pragma unroll
    for (int ni = 0; ni < 4; ++ni) {
      acc[mi][ni][0] = 0.f; acc[mi][ni][1] = 0.f;
      acc[mi][ni][2] = 0.f; acc[mi][ni][3] = 0.f;
    }

  bf16x8 afr[8], bfr[4];

#define STAGE_A(T)                                                             \
  {                                                                            \
    char* sb = smem_g + ((T) & 3) * 32768;                                     \
    gl_lds16(gA0 + (T) * 32, (unsigned short*)(sb + dof0));                    \
    gl_lds16(gA1 + (T) * 32, (unsigned short*)(sb + dof1));                    \
  }
#define STAGE_B(T)                                                             \
  {                                                                            \
    char* sb = smem_g + ((T) & 3) * 32768;                                     \
    gl_lds16(gB0 + (T) * 32, (unsigned short*)(sb + 16384 + dof0));            \
    gl_lds16(gB1 + (T) * 32, (unsigned short*)(sb + 16384 + dof1));            \
  }

#define MFMA_HALF(NL)                                                          \
  {                                                                            \
    asm volatile("s_waitcnt lgkmcnt(0)" ::: "memory");                         \
    __builtin_amdgcn_sched_barrier(0);                                         \
    __builtin_amdgcn_s_setprio(1);                                             \
    _Pragma("unroll")                                                          \
    for (int mi = 0; mi < 8; ++mi) {                                           \
      acc[mi][NL] = __builtin_amdgcn_mfma_f32_16x16x32_bf16(                   \
          afr[mi], bfr[NL], acc[mi][NL], 0, 0, 0);                             \
      acc[mi][(NL) + 1] = __builtin_amdgcn_mfma_f32_16x16x32_bf16(             \
          afr[mi], bfr[(NL) + 1], acc[mi][(NL) + 1], 0, 0, 0);                 \
    }                                                                          \
    __builtin_amdgcn_s_setprio(0);                                             \
    __builtin_amdgcn_s_barrier();                                              \
  }

// Phase A: read A[0..7], B[0..1] of tile T; optionally stage gA(T+3); barrier;
// compute the B0/B1 half (16 MFMA).
#define PHASE_A(T, DOSTAGE)                                                    \
  {                                                                            \
    const char* bb = smem_g + ((T) & 3) * 32768;                               \
    _Pragma("unroll")                                                          \
    for (int mi = 0; mi < 8; ++mi) afr[mi] = *(const bf16x8*)(bb + aoff[mi]);  \
    bfr[0] = *(const bf16x8*)(bb + boff[0]);                                   \
    bfr[1] = *(const bf16x8*)(bb + boff[1]);                                   \
    if (DOSTAGE) STAGE_A((T) + 3);                                             \
    __builtin_amdgcn_s_barrier();                                              \
    MFMA_HALF(0)                                                               \
  }

// Phase B: read B[2..3] of tile T (A frags stay live); optionally stage
// gB(T+3); counted vmcnt for tile T+1 readiness; barrier; other half.
#define PHASE_B(T, DOSTAGE, VMSTR)                                             \
  {                                                                            \
    const char* bb = smem_g + ((T) & 3) * 32768;                               \
    bfr[2] = *(const bf16x8*)(bb + boff[2]);                                   \
    bfr[3] = *(const bf16x8*)(bb + boff[3]);                                   \
    if (DOSTAGE) STAGE_B((T) + 3);                                             \
    asm volatile(VMSTR ::: "memory");                                          \
    __builtin_amdgcn_s_barrier();                                              \
    MFMA_HALF(2)                                                               \
  }

  // prologue: tiles 0,1,2 in flight (12 loads/thread); ensure tile 0 landed.
  STAGE_A(0); STAGE_B(0);
  STAGE_A(1); STAGE_B(1);
  STAGE_A(2); STAGE_B(2);
  asm volatile("s_waitcnt vmcnt(8)" ::: "memory");
  __builtin_amdgcn_s_barrier();

  // main loop: 32 K-steps of 32. Steady state: tiles t+1,t+2,t+3 in flight
  // (12 loads); vmcnt(8) drains exactly tile t+1's 4 loads.
  for (int t = 0; t < 29; ++t) {
    PHASE_A(t, 1)
    PHASE_B(t, 1, "s_waitcnt vmcnt(8)")
  }
  PHASE_A(29, 0)
  PHASE_B(29, 0, "s_waitcnt vmcnt(4)")
  PHASE_A(30, 0)
  PHASE_B(30, 0, "s_waitcnt vmcnt(0)")
  PHASE_A(31, 0)
  PHASE_B(31, 0, "s_nop 0")

#undef PHASE_A
#undef PHASE_B
#undef MFMA_HALF
#undef STAGE_A
#undef STAGE_B

  // epilogue: D row = quad*4 + r (M dim), col = l16 (N dim)
#pragma unroll
  for (int ni = 0; ni < 4; ++ni) {
    long gcol = nbase + wn * 64 + ni * 16 + l16;
    float bv = bias[gcol];
#pragma unroll
    for (int mi = 0; mi < 8; ++mi) {
      long grow = mbase + wm * 128 + mi * 16 + quad * 4;
#pragma unroll
      for (int r = 0; r < 4; ++r)
        C[(grow + r) * 3072 + gcol] = acc[mi][ni][r] + bv;
    }
  }
}

// ---------- launcher ----------
extern "C" void kernel_launch(void* const* d_in, const int* in_sizes, int n_in,
                              void* d_out, int out_size, void* d_ws, size_t ws_size,
                              hipStream_t stream) {
  const float* W    = (const float*)d_in[0];  // [3072,1024]
  const float* bias = (const float*)d_in[1];  // [3072]
  const float* x    = (const float*)d_in[2];  // [8,4096,1024]
  const float* qR   = (const float*)d_in[3];  // [8,128,128]
  const float* kR   = (const float*)d_in[4];
  const float* vR   = (const float*)d_in[5];
  float* out = (float*)d_out;                 // [8,4096,3072]

  char* ws = (char*)d_ws;
  float* wsL           = (float*)(ws);                       // 1.5 MB
  float* wsQt          = (float*)(ws + 1572864);             // 1.5 MB
  unsigned short* wsF  = (unsigned short*)(ws + 3145728);    // 6 MB  (filt bf16)
  unsigned short* wsX  = (unsigned short*)(ws + 9437184);    // 64 MB (x bf16)

  static bool attr_done = false;
  if (!attr_done) {
    (void)hipFuncSetAttribute(reinterpret_cast<const void*>(gemm_k),
                              hipFuncAttributeMaxDynamicSharedMemorySize, 131072);
    attr_done = true;
  }

  cayley_cvt_k<<<24 + 2048, 512, 65536, stream>>>(qR, kR, vR, wsL, wsQt,
                                                  (const float4*)x, (ushort4*)wsX,
                                                  33554432 / 4);
  filt_k<<<dim3(24, 16), 256, 0, stream>>>(W, wsQt, wsF);
  gemm_k<<<dim3(12, 128), 512, 131072, stream>>>(wsX, wsF, bias, out);
}